// Round 1
// baseline (4733.324 us; speedup 1.0000x reference)
//
#include <hip/hip_runtime.h>

// Model dims
#define BB 128
#define TT 64
#define EE 512
#define HH 512
#define VV 10000
#define FIN 2048

// persistent recurrence grid
#define NBLK 48
#define NA 32   // phase A (AB gemm) + phase B (softmax) blocks
#define NC 16   // phase C (GX gemm + gate) blocks

typedef __attribute__((ext_vector_type(4))) float f32x4_t;
typedef __attribute__((ext_vector_type(8))) short s16x8_t;

__device__ __forceinline__ unsigned short f2bf(float x) {
    unsigned int u = __float_as_uint(x);
    unsigned int r = (u + 0x7fffu + ((u >> 16) & 1u)) >> 16;
    return (unsigned short)r;
}

// XOR swizzle for LDS weight tiles: row stride 1024 B (512 bf16).
// Unswizzled, lanes m16=0..15 reading the same 16B k-slot are a 16-way bank
// conflict; XOR of (row&7)<<4 spreads 8 rows over 8 distinct 16B slots -> 2-way (free).
__device__ __forceinline__ int swz(int row, int kb) {
    return row * 1024 + (kb ^ ((row & 7) << 4));
}

// ---------------- fp32 GEMM (fc layer only): C[M,N] = A[M,K] @ B[N,K]^T + bias -----
__global__ __launch_bounds__(256) void gemm32(
    const float* __restrict__ A, int lda,
    const float* __restrict__ Bw, int ldb,
    float* __restrict__ C, int ldc, int K,
    const float* __restrict__ bias)
{
    __shared__ float As[32][34];
    __shared__ float Bs[32][34];
    const int tx = threadIdx.x, ty = threadIdx.y;
    const int tid = ty * 16 + tx;
    const int m0 = blockIdx.y * 32, n0 = blockIdx.x * 32;
    const int lr = tid >> 3, lc = (tid & 7) << 2;
    const float* ap = A + (size_t)(m0 + lr) * lda + lc;
    const float* bp = Bw + (size_t)(n0 + lr) * ldb + lc;
    float c00 = 0.f, c01 = 0.f, c10 = 0.f, c11 = 0.f;
    for (int kc = 0; kc < K; kc += 32) {
        float4 av = *(const float4*)(ap + kc);
        float4 bv = *(const float4*)(bp + kc);
        __syncthreads();
        As[lc + 0][lr] = av.x; As[lc + 1][lr] = av.y;
        As[lc + 2][lr] = av.z; As[lc + 3][lr] = av.w;
        Bs[lc + 0][lr] = bv.x; Bs[lc + 1][lr] = bv.y;
        Bs[lc + 2][lr] = bv.z; Bs[lc + 3][lr] = bv.w;
        __syncthreads();
#pragma unroll
        for (int kk = 0; kk < 32; kk++) {
            float2 a = *(const float2*)&As[kk][2 * ty];
            float2 b = *(const float2*)&Bs[kk][2 * tx];
            c00 = fmaf(a.x, b.x, c00); c01 = fmaf(a.x, b.y, c01);
            c10 = fmaf(a.y, b.x, c10); c11 = fmaf(a.y, b.y, c11);
        }
    }
    float cc[2][2] = {{c00, c01}, {c10, c11}};
    const int row = m0 + 2 * ty, col = n0 + 2 * tx;
#pragma unroll
    for (int i = 0; i < 2; i++)
#pragma unroll
        for (int j = 0; j < 2; j++)
            C[(size_t)(row + i) * ldc + col + j] = cc[i][j] + bias[col + j];
}

// ---------------- bf16 MFMA GEMM, 128x128 tile ------------------------------------
// C[M,N] = A[M,K]@B[N,K]^T, M%128==0, K%32==0. grid=(ceil(N/128), M/128).
__global__ __launch_bounds__(256) void gemm128(
    const unsigned short* __restrict__ A, const unsigned short* __restrict__ Bw,
    float* __restrict__ C, int N, int K,
    const float* __restrict__ bias,
    const float* __restrict__ base, int ldbase, int mode)
{
    __shared__ __align__(16) unsigned short As[128 * 32];
    __shared__ __align__(16) unsigned short Bs[128 * 32];
    const int tid = threadIdx.x;
    const int lane = tid & 63, wave = tid >> 6;
    const int bm = blockIdx.y * 128, bn = blockIdx.x * 128;
    const int wm = (wave & 1) * 64, wn = (wave >> 1) * 64;
    const int sr = tid >> 2, sc = (tid & 3) * 8;
    const int m16 = lane & 15, q = lane >> 4;

    f32x4_t acc[4][4];
#pragma unroll
    for (int i = 0; i < 4; i++)
#pragma unroll
        for (int j = 0; j < 4; j++)
            acc[i][j] = (f32x4_t){0.f, 0.f, 0.f, 0.f};

    for (int kc = 0; kc < K; kc += 32) {
        uint4 a0 = *(const uint4*)(A + (size_t)(bm + sr) * K + kc + sc);
        uint4 a1 = *(const uint4*)(A + (size_t)(bm + 64 + sr) * K + kc + sc);
        uint4 b0, b1;
        int rb0 = bn + sr, rb1 = bn + 64 + sr;
        if (rb0 < N) b0 = *(const uint4*)(Bw + (size_t)rb0 * K + kc + sc);
        else { b0.x = 0; b0.y = 0; b0.z = 0; b0.w = 0; }
        if (rb1 < N) b1 = *(const uint4*)(Bw + (size_t)rb1 * K + kc + sc);
        else { b1.x = 0; b1.y = 0; b1.z = 0; b1.w = 0; }
        __syncthreads();
        *(uint4*)(&As[sr * 32 + sc]) = a0;
        *(uint4*)(&As[(sr + 64) * 32 + sc]) = a1;
        *(uint4*)(&Bs[sr * 32 + sc]) = b0;
        *(uint4*)(&Bs[(sr + 64) * 32 + sc]) = b1;
        __syncthreads();

        s16x8_t af[4], bf[4];
#pragma unroll
        for (int i = 0; i < 4; i++) {
            af[i] = *(const s16x8_t*)(&As[(wm + i * 16 + m16) * 32 + q * 8]);
            bf[i] = *(const s16x8_t*)(&Bs[(wn + i * 16 + m16) * 32 + q * 8]);
        }
#pragma unroll
        for (int i = 0; i < 4; i++)
#pragma unroll
            for (int j = 0; j < 4; j++)
                acc[i][j] = __builtin_amdgcn_mfma_f32_16x16x32_bf16(af[i], bf[j], acc[i][j], 0, 0, 0);
    }

#pragma unroll
    for (int i = 0; i < 4; i++)
#pragma unroll
        for (int j = 0; j < 4; j++) {
            int gr = bm + wm + i * 16 + q * 4;
            int gc = bn + wn + j * 16 + m16;
            if (gc < N) {
                if (mode == 0) {
                    float addc = bias ? bias[gc] : 0.f;
#pragma unroll
                    for (int rr = 0; rr < 4; rr++) {
                        float v = acc[i][j][rr] + addc;
                        if (base) v += base[(size_t)(gr + rr) * ldbase + gc];
                        C[(size_t)(gr + rr) * N + gc] = v;
                    }
                } else {
#pragma unroll
                    for (int rr = 0; rr < 4; rr++) {
                        int r = gr + rr;
                        float v = acc[i][j][rr];
                        v += (gc < 512) ? base[r * 512 + gc] : bias[gc - 512];
                        C[(size_t)r * N + gc] = v;
                    }
                }
            }
        }
}

// ---------------- bf16 MFMA GEMM, 64x64 tile (prep-only now) -----------------------
__global__ __launch_bounds__(256) void gemm64(
    const unsigned short* __restrict__ A, const unsigned short* __restrict__ Bw,
    float* __restrict__ C, int N, int K,
    const float* __restrict__ bias,
    const float* __restrict__ base, int ldbase, int mode)
{
    __shared__ __align__(16) unsigned short As[64 * 32];
    __shared__ __align__(16) unsigned short Bs[64 * 32];
    const int tid = threadIdx.x;
    const int lane = tid & 63, wave = tid >> 6;
    const int bm = blockIdx.y * 64, bn = blockIdx.x * 64;
    const int wm = (wave & 1) * 32, wn = (wave >> 1) * 32;
    const int sr = tid >> 2, sc = (tid & 3) * 8;
    const int m16 = lane & 15, q = lane >> 4;

    f32x4_t acc[2][2];
#pragma unroll
    for (int i = 0; i < 2; i++)
#pragma unroll
        for (int j = 0; j < 2; j++)
            acc[i][j] = (f32x4_t){0.f, 0.f, 0.f, 0.f};

    for (int kc = 0; kc < K; kc += 32) {
        uint4 a0 = *(const uint4*)(A + (size_t)(bm + sr) * K + kc + sc);
        uint4 b0 = *(const uint4*)(Bw + (size_t)(bn + sr) * K + kc + sc);
        __syncthreads();
        *(uint4*)(&As[sr * 32 + sc]) = a0;
        *(uint4*)(&Bs[sr * 32 + sc]) = b0;
        __syncthreads();

        s16x8_t af[2], bf[2];
#pragma unroll
        for (int i = 0; i < 2; i++) {
            af[i] = *(const s16x8_t*)(&As[(wm + i * 16 + m16) * 32 + q * 8]);
            bf[i] = *(const s16x8_t*)(&Bs[(wn + i * 16 + m16) * 32 + q * 8]);
        }
#pragma unroll
        for (int i = 0; i < 2; i++)
#pragma unroll
            for (int j = 0; j < 2; j++)
                acc[i][j] = __builtin_amdgcn_mfma_f32_16x16x32_bf16(af[i], bf[j], acc[i][j], 0, 0, 0);
    }

#pragma unroll
    for (int i = 0; i < 2; i++)
#pragma unroll
        for (int j = 0; j < 2; j++) {
            int gr = bm + wm + i * 16 + q * 4;
            int gc = bn + wn + j * 16 + m16;
            if (mode == 0) {
                float addc = bias ? bias[gc] : 0.f;
#pragma unroll
                for (int rr = 0; rr < 4; rr++) {
                    float v = acc[i][j][rr] + addc;
                    if (base) v += base[(size_t)(gr + rr) * ldbase + gc];
                    C[(size_t)(gr + rr) * N + gc] = v;
                }
            } else {
#pragma unroll
                for (int rr = 0; rr < 4; rr++) {
                    int r = gr + rr;
                    float v = acc[i][j][rr];
                    v += (gc < 512) ? base[r * 512 + gc] : bias[gc - 512];
                    C[(size_t)r * N + gc] = v;
                }
            }
        }
}

// ---------------- BatchNorm1d (training stats over B=128) --------------------------
__global__ __launch_bounds__(128) void bn_kernel(
    const float* __restrict__ f, const float* __restrict__ gamma,
    const float* __restrict__ beta, float* __restrict__ feats)
{
    int e = blockIdx.x, b = threadIdx.x;
    float v = f[b * EE + e];
    __shared__ float s1[128], s2[128];
    s1[b] = v; s2[b] = v * v;
    __syncthreads();
    for (int s = 64; s > 0; s >>= 1) {
        if (b < s) { s1[b] += s1[b + s]; s2[b] += s2[b + s]; }
        __syncthreads();
    }
    float mu = s1[0] * (1.f / 128.f);
    float var = s2[0] * (1.f / 128.f) - mu * mu;
    float inv = 1.f / sqrtf(var + 1e-5f);
    feats[b * EE + e] = gamma[e] * (v - mu) * inv + beta[e];
}

// ---------------- build Xb[t][b][:] in bf16 ---------------------------------------
__global__ void build_x_bf16(const float* __restrict__ feats, const float* __restrict__ embW,
                             const int* __restrict__ cap, unsigned short* __restrict__ Xb)
{
    int id = blockIdx.x * 256 + threadIdx.x;   // 1,048,576 groups of 4
    int e4 = id & 127;
    int rem = id >> 7;
    int b = rem & 127;
    int t = rem >> 7;
    const float4* src;
    if (t == 0) src = (const float4*)(feats + b * EE) + e4;
    else        src = (const float4*)(embW + (size_t)cap[b * TT + t - 1] * EE) + e4;
    float4 v = *src;
    ushort4 o;
    o.x = f2bf(v.x); o.y = f2bf(v.y); o.z = f2bf(v.z); o.w = f2bf(v.w);
    ((ushort4*)Xb)[(size_t)(t * BB + b) * 128 + e4] = o;
}

// ---------------- weight pack/convert kernels -------------------------------------
__global__ void cvt_bf16(const float* __restrict__ src, unsigned short* __restrict__ dst, int n)
{
    int i = blockIdx.x * 256 + threadIdx.x;
    if (i < n) dst[i] = f2bf(src[i]);
}

// attn_Wxb[n,e] = attn_W[n*1024 + e]
__global__ void pack_attn_wx(const float* __restrict__ attnW, unsigned short* __restrict__ dst)
{
    int i = blockIdx.x * 256 + threadIdx.x;    // 262,144
    int n = i >> 9, e = i & 511;
    dst[i] = f2bf(attnW[n * 1024 + e]);
}

// CxTb[e,n] = comb_W[n*1024 + e]
__global__ void pack_cxt(const float* __restrict__ combW, unsigned short* __restrict__ dst)
{
    int i = blockIdx.x * 256 + threadIdx.x;    // 262,144
    int e = i >> 9, n = i & 511;
    dst[i] = f2bf(combW[n * 1024 + e]);
}

// WaTb[m,n] = comb_W[n*1024 + 512 + m]
__global__ void pack_wat(const float* __restrict__ combW, unsigned short* __restrict__ dst)
{
    int i = blockIdx.x * 256 + threadIdx.x;    // 262,144
    int m = i >> 9, n = i & 511;
    dst[i] = f2bf(combW[n * 1024 + 512 + m]);
}

// Wcatb[j,k]: j<512 -> attn_W[j,512+k]; else Whh[j-512,k]
__global__ void pack_wcat_bf(const float* __restrict__ attnW, const float* __restrict__ Whh,
                             unsigned short* __restrict__ dst)
{
    int i = blockIdx.x * 256 + threadIdx.x;    // 1,048,576
    int j = i >> 9, k = i & 511;
    dst[i] = f2bf((j < 512) ? attnW[j * 1024 + 512 + k]
                            : Whh[(size_t)(j - 512) * 512 + k]);
}

// bias2[j] = bih[j] + dot(Wih[j,:], comb_b)
__global__ void bias2_kernel(const float* __restrict__ Wih, const float* __restrict__ comb_b,
                             const float* __restrict__ bih, float* __restrict__ bias2)
{
    int j = blockIdx.x, lane = threadIdx.x;   // grid 1536, block 64
    float s = 0.f;
    for (int n = lane; n < 512; n += 64) s += Wih[(size_t)j * 512 + n] * comb_b[n];
    for (int o = 32; o > 0; o >>= 1) s += __shfl_down(s, o);
    if (lane == 0) bias2[j] = bih[j] + s;
}

__global__ void zero_u32(unsigned int* __restrict__ p) { *p = 0u; }

// ---------------- persistent recurrence kernel ------------------------------------
// Grid = NBLK blocks x 256 threads. Blocks 0..31: AB gemm (phase A) + softmax/APP
// (phase B). Blocks 32..47: GX gemm + GRU gate (phase C). Weight slices live in LDS
// across all 64 steps (XOR-swizzled); per-step tensors move through L2.
// 3 grid barriers per step (device-scope atomic arrive + spin).
__device__ __forceinline__ void gbar(unsigned int* cnt, unsigned int tgt)
{
    __syncthreads();
    if (threadIdx.x == 0) {
        __threadfence();  // release prior global writes (agent scope)
        __hip_atomic_fetch_add(cnt, 1u, __ATOMIC_ACQ_REL, __HIP_MEMORY_SCOPE_AGENT);
        while (__hip_atomic_load(cnt, __ATOMIC_RELAXED, __HIP_MEMORY_SCOPE_AGENT) < tgt)
            __builtin_amdgcn_s_sleep(2);
        __threadfence();  // acquire: invalidate L1/L2 before consuming peers' writes
    }
    __syncthreads();
}

__global__ __launch_bounds__(256) void recurrence(
    const unsigned short* __restrict__ Wcatb,   // [2048,512] bf16
    const unsigned short* __restrict__ W_acb,   // [1536,512] bf16
    const unsigned short* __restrict__ h0b,     // [128,512] bf16
    const float* __restrict__ h0,               // [128,512]
    const float* __restrict__ Lx,               // [T,128,512]
    const float* __restrict__ GxX,              // [T,128,1536]
    const float* __restrict__ feats,            // [128,512]
    const float* __restrict__ bhh,              // [1536]
    float* __restrict__ AB,                     // [128,2048] scratch
    unsigned short* __restrict__ APPb,          // [128,512] scratch bf16
    float* __restrict__ HS,                     // [T,128,512]
    unsigned short* __restrict__ HSb,           // [T,128,512] bf16
    unsigned int* __restrict__ barcnt)
{
    __shared__ __align__(16) unsigned char smem[96 * 1024];
    const int tid = threadIdx.x;
    const int bid = blockIdx.x;
    const int lane = tid & 63, wave = tid >> 6;
    const int m16 = lane & 15, q = lane >> 4;

    // ---- preload persistent weight slices into LDS (swizzled) ----
    if (bid < NA) {
        // 64 rows of Wcat: output cols bid*64 .. +63
        const uint4* src = (const uint4*)(Wcatb + (size_t)bid * 64 * 512);
#pragma unroll
        for (int it = 0; it < 16; it++) {
            int idx = it * 256 + tid;          // 4096 x 16B
            int r = idx >> 6, sl = idx & 63;
            *(uint4*)(smem + swz(r, sl * 16)) = src[idx];
        }
    } else {
        // 96 rows of W_ac: parts {n, 512+n, 1024+n}, n0 = (bid-32)*32
        const int n0c = (bid - NA) * 32;
#pragma unroll
        for (int it = 0; it < 24; it++) {
            int idx = it * 256 + tid;          // 6144 x 16B
            int r = idx >> 6, sl = idx & 63;
            int p = r >> 5, rr = r & 31;
            *(uint4*)(smem + swz(r, sl * 16)) =
                ((const uint4*)(W_acb + (size_t)(p * 512 + n0c + rr) * 512))[sl];
        }
    }
    __syncthreads();

    unsigned int tgt = 0;

    for (int t = 0; t < TT; t++) {
        const unsigned short* hb = t ? (HSb + (size_t)(t - 1) * (BB * HH)) : h0b;
        const float* hprev = t ? (HS + (size_t)(t - 1) * (BB * HH)) : h0;
        const float* Lxt = Lx + (size_t)t * (BB * HH);
        const float* GxXt = GxX + (size_t)t * (BB * 1536);

        // ---- phase A: AB[:, n0..n0+63] = h @ Wcat_slice^T + base ----
        if (bid < NA) {
            const int n0 = bid * 64;
            const int rowhalf = (wave >> 1) * 64;
            const int colhalf = (wave & 1) * 32;
            f32x4_t acc[4][2];
#pragma unroll
            for (int i = 0; i < 4; i++)
#pragma unroll
                for (int j = 0; j < 2; j++)
                    acc[i][j] = (f32x4_t){0.f, 0.f, 0.f, 0.f};
            for (int kc = 0; kc < 512; kc += 32) {
                const int kb = (kc + q * 8) * 2;
                s16x8_t af[4];
#pragma unroll
                for (int i = 0; i < 4; i++)
                    af[i] = *(const s16x8_t*)(hb + (size_t)(rowhalf + i * 16 + m16) * 512 + kc + q * 8);
                s16x8_t bfr[2];
#pragma unroll
                for (int j = 0; j < 2; j++)
                    bfr[j] = *(const s16x8_t*)(smem + swz(colhalf + j * 16 + m16, kb));
#pragma unroll
                for (int i = 0; i < 4; i++)
#pragma unroll
                    for (int j = 0; j < 2; j++)
                        acc[i][j] = __builtin_amdgcn_mfma_f32_16x16x32_bf16(af[i], bfr[j], acc[i][j], 0, 0, 0);
            }
#pragma unroll
            for (int i = 0; i < 4; i++)
#pragma unroll
                for (int j = 0; j < 2; j++) {
                    const int b0 = rowhalf + i * 16 + q * 4;
                    const int col = n0 + colhalf + j * 16 + m16;
#pragma unroll
                    for (int rr = 0; rr < 4; rr++) {
                        const int b = b0 + rr;
                        float v = acc[i][j][rr] +
                                  ((col < 512) ? Lxt[b * 512 + col] : bhh[col - 512]);
                        AB[b * 2048 + col] = v;
                    }
                }
        }
        tgt += NBLK; gbar(barcnt, tgt);

        // ---- phase B: softmax over AB[:,0:512] + APP = feats*aw (bf16) ----
        if (bid < NA) {
            const int row = bid * 4 + wave;           // 32 blocks x 4 waves = 128 rows
            const float* Lr = AB + row * 2048 + lane * 8;
            float4 x0 = *(const float4*)(Lr);
            float4 x1 = *(const float4*)(Lr + 4);
            float vm = fmaxf(fmaxf(fmaxf(x0.x, x0.y), fmaxf(x0.z, x0.w)),
                             fmaxf(fmaxf(x1.x, x1.y), fmaxf(x1.z, x1.w)));
#pragma unroll
            for (int o = 32; o > 0; o >>= 1) vm = fmaxf(vm, __shfl_xor(vm, o));
            float e0 = __expf(x0.x - vm), e1 = __expf(x0.y - vm);
            float e2 = __expf(x0.z - vm), e3 = __expf(x0.w - vm);
            float e4 = __expf(x1.x - vm), e5 = __expf(x1.y - vm);
            float e6 = __expf(x1.z - vm), e7 = __expf(x1.w - vm);
            float s = ((e0 + e1) + (e2 + e3)) + ((e4 + e5) + (e6 + e7));
#pragma unroll
            for (int o = 32; o > 0; o >>= 1) s += __shfl_xor(s, o);
            const float inv = 1.f / s;
            const float* fr = feats + row * 512 + lane * 8;
            float4 f0 = *(const float4*)(fr);
            float4 f1 = *(const float4*)(fr + 4);
            s16x8_t ov;
            ov[0] = (short)f2bf(f0.x * e0 * inv);
            ov[1] = (short)f2bf(f0.y * e1 * inv);
            ov[2] = (short)f2bf(f0.z * e2 * inv);
            ov[3] = (short)f2bf(f0.w * e3 * inv);
            ov[4] = (short)f2bf(f1.x * e4 * inv);
            ov[5] = (short)f2bf(f1.y * e5 * inv);
            ov[6] = (short)f2bf(f1.z * e6 * inv);
            ov[7] = (short)f2bf(f1.w * e7 * inv);
            *(s16x8_t*)(APPb + row * 512 + lane * 8) = ov;
        }
        tgt += NBLK; gbar(barcnt, tgt);

        // ---- phase C: GX trio gemm + GRU gate + h writeback ----
        if (bid >= NA) {
            const int n0 = (bid - NA) * 32;
            const int rowhalf = (wave >> 1) * 64;
            const int j = wave & 1;
            f32x4_t acc[4][3];
#pragma unroll
            for (int i = 0; i < 4; i++)
#pragma unroll
                for (int p = 0; p < 3; p++)
                    acc[i][p] = (f32x4_t){0.f, 0.f, 0.f, 0.f};
            for (int kc = 0; kc < 512; kc += 32) {
                const int kb = (kc + q * 8) * 2;
                s16x8_t af[4];
#pragma unroll
                for (int i = 0; i < 4; i++)
                    af[i] = *(const s16x8_t*)(APPb + (size_t)(rowhalf + i * 16 + m16) * 512 + kc + q * 8);
                s16x8_t bfr[3];
#pragma unroll
                for (int p = 0; p < 3; p++)
                    bfr[p] = *(const s16x8_t*)(smem + swz(p * 32 + j * 16 + m16, kb));
#pragma unroll
                for (int i = 0; i < 4; i++)
#pragma unroll
                    for (int p = 0; p < 3; p++)
                        acc[i][p] = __builtin_amdgcn_mfma_f32_16x16x32_bf16(af[i], bfr[p], acc[i][p], 0, 0, 0);
            }
            const int n = n0 + j * 16 + m16;
            float* HSt = HS + (size_t)t * (BB * HH);
            unsigned short* HSbt = HSb + (size_t)t * (BB * HH);
#pragma unroll
            for (int i = 0; i < 4; i++) {
                const int b0 = rowhalf + i * 16 + q * 4;
#pragma unroll
                for (int rr = 0; rr < 4; rr++) {
                    const int b = b0 + rr;
                    float xr = acc[i][0][rr] + GxXt[b * 1536 + n];
                    float xz = acc[i][1][rr] + GxXt[b * 1536 + 512 + n];
                    float xn = acc[i][2][rr] + GxXt[b * 1536 + 1024 + n];
                    float hr = AB[b * 2048 + 512 + n];
                    float hz = AB[b * 2048 + 1024 + n];
                    float hn = AB[b * 2048 + 1536 + n];
                    float r = 1.f / (1.f + __expf(-(xr + hr)));
                    float z = 1.f / (1.f + __expf(-(xz + hz)));
                    float nt = tanhf(xn + r * hn);
                    float h = (1.f - z) * nt + z * hprev[b * 512 + n];
                    HSt[b * 512 + n] = h;
                    HSbt[b * 512 + n] = f2bf(h);
                }
            }
        }
        tgt += NBLK; gbar(barcnt, tgt);
    }
}

// ---------------- fused log-softmax: one read + one write per row ------------------
__global__ __launch_bounds__(256) void logsoftmax_k(float* __restrict__ C)
{
    __shared__ float4 buf[2500];   // one 10000-float row (40 KB)
    __shared__ float red[8];
    const int row = blockIdx.x, tid = threadIdx.x;
    float4* p = (float4*)(C + (size_t)row * VV);
    float m = -1e30f;
    for (int i = tid; i < 2500; i += 256) {
        float4 v = p[i];
        buf[i] = v;
        m = fmaxf(fmaxf(fmaxf(v.x, v.y), fmaxf(v.z, v.w)), m);
    }
#pragma unroll
    for (int o = 32; o > 0; o >>= 1) m = fmaxf(m, __shfl_xor(m, o));
    if ((tid & 63) == 0) red[tid >> 6] = m;
    __syncthreads();
    m = fmaxf(fmaxf(red[0], red[1]), fmaxf(red[2], red[3]));
    float s = 0.f;
    for (int i = tid; i < 2500; i += 256) {
        float4 v = buf[i];
        s += __expf(v.x - m) + __expf(v.y - m) + __expf(v.z - m) + __expf(v.w - m);
    }
#pragma unroll
    for (int o = 32; o > 0; o >>= 1) s += __shfl_xor(s, o);
    if ((tid & 63) == 0) red[4 + (tid >> 6)] = s;
    __syncthreads();
    const float l = m + logf(red[4] + red[5] + red[6] + red[7]);
    for (int i = tid; i < 2500; i += 256) {
        float4 v = buf[i];
        v.x -= l; v.y -= l; v.z -= l; v.w -= l;
        p[i] = v;
    }
}

// ---------------- hiddens: [T,B,H] -> [B,T,H] -------------------------------------
__global__ void copy_hiddens(const float* __restrict__ HS, float* __restrict__ out)
{
    int id = blockIdx.x * 256 + threadIdx.x;   // 1,048,576 float4
    int h4 = id & 127;
    int t = (id >> 7) & 63;
    int b = id >> 13;
    ((float4*)out)[id] = ((const float4*)HS)[t * 16384 + b * 128 + h4];
}

// ===================================================================================
extern "C" void kernel_launch(void* const* d_in, const int* in_sizes, int n_in,
                              void* d_out, int out_size, void* d_ws, size_t ws_size,
                              hipStream_t stream)
{
    const float* features = (const float*)d_in[0];
    const int*   captions = (const int*)d_in[1];
    const float* h0       = (const float*)d_in[2];
    const float* embed_W  = (const float*)d_in[4];
    const float* fc_W     = (const float*)d_in[5];
    const float* fc_b     = (const float*)d_in[6];
    const float* bn_gamma = (const float*)d_in[7];
    const float* bn_beta  = (const float*)d_in[8];
    const float* attn_W   = (const float*)d_in[9];
    const float* attn_b   = (const float*)d_in[10];
    const float* comb_W   = (const float*)d_in[11];
    const float* comb_b   = (const float*)d_in[12];
    const float* gru_Wih  = (const float*)d_in[13];
    const float* gru_Whh  = (const float*)d_in[14];
    const float* gru_bih  = (const float*)d_in[15];
    const float* gru_bhh  = (const float*)d_in[16];
    const float* out_W    = (const float*)d_in[17];
    const float* out_b    = (const float*)d_in[18];
    float* dout = (float*)d_out;

    // workspace layout
    float* w      = (float*)d_ws;
    float* f      = w;                    //    65,536
    float* feats  = w + 65536;            //    65,536
    float* Lx     = w + 131072;           // 4,194,304
    float* GxX    = w + 4325376;          // 12,582,912
    float* HS     = w + 16908288;         // 4,194,304
    float* W2     = w + 21102592;         //   786,432
    float* W_ac   = w + 21889024;         //   786,432
    float* AB     = w + 22675456;         //   262,144
    unsigned int* barcnt = (unsigned int*)(w + 22937600);  // (old GX region)
    float* bias2  = w + 23134208;         //     1,536
    unsigned short* u      = (unsigned short*)(w + 23143936);
    unsigned short* Xb     = u;             // 4,194,304
    unsigned short* attnWxb= u + 4194304;   //   262,144
    unsigned short* Wihb   = u + 4456448;   //   786,432
    unsigned short* CxTb   = u + 5242880;   //   262,144
    unsigned short* WaTb   = u + 5505024;   //   262,144
    unsigned short* Wcatb  = u + 5767168;   // 1,048,576
    unsigned short* W2b    = u + 6815744;   //   786,432
    unsigned short* W_acb  = u + 7602176;   //   786,432
    unsigned short* outWb  = u + 8388608;   // 5,120,000
    unsigned short* HSb    = u + 13508608;  // 4,194,304
    unsigned short* APPb   = u + 17702912;  //    65,536
    unsigned short* h0b    = u + 17768448;  //    65,536

    dim3 blk2(16, 16);

    // ---- prep ----
    gemm32<<<dim3(16, 4), blk2, 0, stream>>>(features, FIN, fc_W, FIN, f, EE, FIN, fc_b);
    bn_kernel<<<512, 128, 0, stream>>>(f, bn_gamma, bn_beta, feats);
    cvt_bf16<<<256, 256, 0, stream>>>(h0, h0b, BB * HH);
    build_x_bf16<<<4096, 256, 0, stream>>>(feats, embed_W, captions, Xb);
    pack_attn_wx<<<1024, 256, 0, stream>>>(attn_W, attnWxb);
    pack_cxt<<<1024, 256, 0, stream>>>(comb_W, CxTb);
    pack_wat<<<1024, 256, 0, stream>>>(comb_W, WaTb);
    pack_wcat_bf<<<4096, 256, 0, stream>>>(attn_W, gru_Whh, Wcatb);
    cvt_bf16<<<3072, 256, 0, stream>>>(gru_Wih, Wihb, 1536 * 512);
    cvt_bf16<<<20000, 256, 0, stream>>>(out_W, outWb, VV * HH);
    bias2_kernel<<<1536, 64, 0, stream>>>(gru_Wih, comb_b, gru_bih, bias2);
    zero_u32<<<1, 1, 0, stream>>>(barcnt);

    // Lx = X @ attn_Wx^T + attn_b        [8192, 512]
    gemm128<<<dim3(4, 64), 256, 0, stream>>>(Xb, attnWxb, Lx, 512, 512,
                                             attn_b, nullptr, 0, 0);
    // W2 = Wih @ comb_Wx                  [1536, 512]
    gemm64<<<dim3(8, 24), 256, 0, stream>>>(Wihb, CxTb, W2, 512, 512,
                                            nullptr, nullptr, 0, 0);
    cvt_bf16<<<3072, 256, 0, stream>>>(W2, W2b, 1536 * 512);
    // GxX = X @ W2^T + bias2              [8192, 1536]
    gemm128<<<dim3(12, 64), 256, 0, stream>>>(Xb, W2b, GxX, 1536, 512,
                                              bias2, nullptr, 0, 0);
    // W_ac = Wih @ comb_Wa                [1536, 512]
    gemm64<<<dim3(8, 24), 256, 0, stream>>>(Wihb, WaTb, W_ac, 512, 512,
                                            nullptr, nullptr, 0, 0);
    cvt_bf16<<<3072, 256, 0, stream>>>(W_ac, W_acb, 1536 * 512);

    // ---- recurrence: single persistent kernel, all 64 steps ----
    recurrence<<<NBLK, 256, 0, stream>>>(Wcatb, W_acb, h0b, h0, Lx, GxX, feats,
                                         gru_bhh, AB, APPb, HS, HSb, barcnt);

    // ---- output head ----
    gemm128<<<dim3(79, 64), 256, 0, stream>>>(HSb, outWb, dout, VV, 512,
                                              out_b, nullptr, 0, 0);
    logsoftmax_k<<<8192, 256, 0, stream>>>(dout);
    copy_hiddens<<<4096, 256, 0, stream>>>(HS, dout + (size_t)TT * BB * VV);
}

// Round 2
// 4118.505 us; speedup vs baseline: 1.1493x; 1.1493x over previous
//
#include <hip/hip_runtime.h>

// Model dims
#define BB 128
#define TT 64
#define EE 512
#define HH 512
#define VV 10000
#define FIN 2048

typedef __attribute__((ext_vector_type(4))) float f32x4_t;
typedef __attribute__((ext_vector_type(8))) short s16x8_t;

__device__ __forceinline__ unsigned short f2bf(float x) {
    unsigned int u = __float_as_uint(x);
    unsigned int r = (u + 0x7fffu + ((u >> 16) & 1u)) >> 16;
    return (unsigned short)r;
}

// XOR swizzle for LDS tiles with 1024 B row stride (512 bf16 cols).
// 16 lanes reading the same 16B k-slot of 16 consecutive rows spread over
// 8 distinct 16B slots -> 2-way bank aliasing (free).
__device__ __forceinline__ int swz(int row, int kb) {
    return row * 1024 + (kb ^ ((row & 7) << 4));
}

// ---------------- fp32 GEMM (fc layer only): C[M,N] = A[M,K] @ B[N,K]^T + bias -----
__global__ __launch_bounds__(256) void gemm32(
    const float* __restrict__ A, int lda,
    const float* __restrict__ Bw, int ldb,
    float* __restrict__ C, int ldc, int K,
    const float* __restrict__ bias)
{
    __shared__ float As[32][34];
    __shared__ float Bs[32][34];
    const int tx = threadIdx.x, ty = threadIdx.y;
    const int tid = ty * 16 + tx;
    const int m0 = blockIdx.y * 32, n0 = blockIdx.x * 32;
    const int lr = tid >> 3, lc = (tid & 7) << 2;
    const float* ap = A + (size_t)(m0 + lr) * lda + lc;
    const float* bp = Bw + (size_t)(n0 + lr) * ldb + lc;
    float c00 = 0.f, c01 = 0.f, c10 = 0.f, c11 = 0.f;
    for (int kc = 0; kc < K; kc += 32) {
        float4 av = *(const float4*)(ap + kc);
        float4 bv = *(const float4*)(bp + kc);
        __syncthreads();
        As[lc + 0][lr] = av.x; As[lc + 1][lr] = av.y;
        As[lc + 2][lr] = av.z; As[lc + 3][lr] = av.w;
        Bs[lc + 0][lr] = bv.x; Bs[lc + 1][lr] = bv.y;
        Bs[lc + 2][lr] = bv.z; Bs[lc + 3][lr] = bv.w;
        __syncthreads();
#pragma unroll
        for (int kk = 0; kk < 32; kk++) {
            float2 a = *(const float2*)&As[kk][2 * ty];
            float2 b = *(const float2*)&Bs[kk][2 * tx];
            c00 = fmaf(a.x, b.x, c00); c01 = fmaf(a.x, b.y, c01);
            c10 = fmaf(a.y, b.x, c10); c11 = fmaf(a.y, b.y, c11);
        }
    }
    float cc[2][2] = {{c00, c01}, {c10, c11}};
    const int row = m0 + 2 * ty, col = n0 + 2 * tx;
#pragma unroll
    for (int i = 0; i < 2; i++)
#pragma unroll
        for (int j = 0; j < 2; j++)
            C[(size_t)(row + i) * ldc + col + j] = cc[i][j] + bias[col + j];
}

// ---------------- bf16 MFMA GEMM, 128x128 tile ------------------------------------
// C[M,N] = A[M,K]@B[N,K]^T, M%128==0, K%32==0. grid=(ceil(N/128), M/128).
__global__ __launch_bounds__(256) void gemm128(
    const unsigned short* __restrict__ A, const unsigned short* __restrict__ Bw,
    float* __restrict__ C, int N, int K,
    const float* __restrict__ bias,
    const float* __restrict__ base, int ldbase, int mode)
{
    __shared__ __align__(16) unsigned short As[128 * 32];
    __shared__ __align__(16) unsigned short Bs[128 * 32];
    const int tid = threadIdx.x;
    const int lane = tid & 63, wave = tid >> 6;
    const int bm = blockIdx.y * 128, bn = blockIdx.x * 128;
    const int wm = (wave & 1) * 64, wn = (wave >> 1) * 64;
    const int sr = tid >> 2, sc = (tid & 3) * 8;
    const int m16 = lane & 15, q = lane >> 4;

    f32x4_t acc[4][4];
#pragma unroll
    for (int i = 0; i < 4; i++)
#pragma unroll
        for (int j = 0; j < 4; j++)
            acc[i][j] = (f32x4_t){0.f, 0.f, 0.f, 0.f};

    for (int kc = 0; kc < K; kc += 32) {
        uint4 a0 = *(const uint4*)(A + (size_t)(bm + sr) * K + kc + sc);
        uint4 a1 = *(const uint4*)(A + (size_t)(bm + 64 + sr) * K + kc + sc);
        uint4 b0, b1;
        int rb0 = bn + sr, rb1 = bn + 64 + sr;
        if (rb0 < N) b0 = *(const uint4*)(Bw + (size_t)rb0 * K + kc + sc);
        else { b0.x = 0; b0.y = 0; b0.z = 0; b0.w = 0; }
        if (rb1 < N) b1 = *(const uint4*)(Bw + (size_t)rb1 * K + kc + sc);
        else { b1.x = 0; b1.y = 0; b1.z = 0; b1.w = 0; }
        __syncthreads();
        *(uint4*)(&As[sr * 32 + sc]) = a0;
        *(uint4*)(&As[(sr + 64) * 32 + sc]) = a1;
        *(uint4*)(&Bs[sr * 32 + sc]) = b0;
        *(uint4*)(&Bs[(sr + 64) * 32 + sc]) = b1;
        __syncthreads();

        s16x8_t af[4], bf[4];
#pragma unroll
        for (int i = 0; i < 4; i++) {
            af[i] = *(const s16x8_t*)(&As[(wm + i * 16 + m16) * 32 + q * 8]);
            bf[i] = *(const s16x8_t*)(&Bs[(wn + i * 16 + m16) * 32 + q * 8]);
        }
#pragma unroll
        for (int i = 0; i < 4; i++)
#pragma unroll
            for (int j = 0; j < 4; j++)
                acc[i][j] = __builtin_amdgcn_mfma_f32_16x16x32_bf16(af[i], bf[j], acc[i][j], 0, 0, 0);
    }

#pragma unroll
    for (int i = 0; i < 4; i++)
#pragma unroll
        for (int j = 0; j < 4; j++) {
            int gr = bm + wm + i * 16 + q * 4;
            int gc = bn + wn + j * 16 + m16;
            if (gc < N) {
                if (mode == 0) {
                    float addc = bias ? bias[gc] : 0.f;
#pragma unroll
                    for (int rr = 0; rr < 4; rr++) {
                        float v = acc[i][j][rr] + addc;
                        if (base) v += base[(size_t)(gr + rr) * ldbase + gc];
                        C[(size_t)(gr + rr) * N + gc] = v;
                    }
                } else {
#pragma unroll
                    for (int rr = 0; rr < 4; rr++) {
                        int r = gr + rr;
                        float v = acc[i][j][rr];
                        v += (gc < 512) ? base[r * 512 + gc] : bias[gc - 512];
                        C[(size_t)r * N + gc] = v;
                    }
                }
            }
        }
}

// ---------------- bf16 MFMA GEMM, 64x64 tile --------------------------------------
__global__ __launch_bounds__(256) void gemm64(
    const unsigned short* __restrict__ A, const unsigned short* __restrict__ Bw,
    float* __restrict__ C, int N, int K,
    const float* __restrict__ bias,
    const float* __restrict__ base, int ldbase, int mode)
{
    __shared__ __align__(16) unsigned short As[64 * 32];
    __shared__ __align__(16) unsigned short Bs[64 * 32];
    const int tid = threadIdx.x;
    const int lane = tid & 63, wave = tid >> 6;
    const int bm = blockIdx.y * 64, bn = blockIdx.x * 64;
    const int wm = (wave & 1) * 32, wn = (wave >> 1) * 32;
    const int sr = tid >> 2, sc = (tid & 3) * 8;
    const int m16 = lane & 15, q = lane >> 4;

    f32x4_t acc[2][2];
#pragma unroll
    for (int i = 0; i < 2; i++)
#pragma unroll
        for (int j = 0; j < 2; j++)
            acc[i][j] = (f32x4_t){0.f, 0.f, 0.f, 0.f};

    for (int kc = 0; kc < K; kc += 32) {
        uint4 a0 = *(const uint4*)(A + (size_t)(bm + sr) * K + kc + sc);
        uint4 b0 = *(const uint4*)(Bw + (size_t)(bn + sr) * K + kc + sc);
        __syncthreads();
        *(uint4*)(&As[sr * 32 + sc]) = a0;
        *(uint4*)(&Bs[sr * 32 + sc]) = b0;
        __syncthreads();

        s16x8_t af[2], bf[2];
#pragma unroll
        for (int i = 0; i < 2; i++) {
            af[i] = *(const s16x8_t*)(&As[(wm + i * 16 + m16) * 32 + q * 8]);
            bf[i] = *(const s16x8_t*)(&Bs[(wn + i * 16 + m16) * 32 + q * 8]);
        }
#pragma unroll
        for (int i = 0; i < 2; i++)
#pragma unroll
            for (int j = 0; j < 2; j++)
                acc[i][j] = __builtin_amdgcn_mfma_f32_16x16x32_bf16(af[i], bf[j], acc[i][j], 0, 0, 0);
    }

#pragma unroll
    for (int i = 0; i < 2; i++)
#pragma unroll
        for (int j = 0; j < 2; j++) {
            int gr = bm + wm + i * 16 + q * 4;
            int gc = bn + wn + j * 16 + m16;
            if (mode == 0) {
                float addc = bias ? bias[gc] : 0.f;
#pragma unroll
                for (int rr = 0; rr < 4; rr++) {
                    float v = acc[i][j][rr] + addc;
                    if (base) v += base[(size_t)(gr + rr) * ldbase + gc];
                    C[(size_t)(gr + rr) * N + gc] = v;
                }
            } else {
#pragma unroll
                for (int rr = 0; rr < 4; rr++) {
                    int r = gr + rr;
                    float v = acc[i][j][rr];
                    v += (gc < 512) ? base[r * 512 + gc] : bias[gc - 512];
                    C[(size_t)r * N + gc] = v;
                }
            }
        }
}

// ---------------- BatchNorm1d (training stats over B=128) --------------------------
__global__ __launch_bounds__(128) void bn_kernel(
    const float* __restrict__ f, const float* __restrict__ gamma,
    const float* __restrict__ beta, float* __restrict__ feats)
{
    int e = blockIdx.x, b = threadIdx.x;
    float v = f[b * EE + e];
    __shared__ float s1[128], s2[128];
    s1[b] = v; s2[b] = v * v;
    __syncthreads();
    for (int s = 64; s > 0; s >>= 1) {
        if (b < s) { s1[b] += s1[b + s]; s2[b] += s2[b + s]; }
        __syncthreads();
    }
    float mu = s1[0] * (1.f / 128.f);
    float var = s2[0] * (1.f / 128.f) - mu * mu;
    float inv = 1.f / sqrtf(var + 1e-5f);
    feats[b * EE + e] = gamma[e] * (v - mu) * inv + beta[e];
}

// ---------------- build Xb[t][b][:] in bf16 ---------------------------------------
__global__ void build_x_bf16(const float* __restrict__ feats, const float* __restrict__ embW,
                             const int* __restrict__ cap, unsigned short* __restrict__ Xb)
{
    int id = blockIdx.x * 256 + threadIdx.x;   // 1,048,576 groups of 4
    int e4 = id & 127;
    int rem = id >> 7;
    int b = rem & 127;
    int t = rem >> 7;
    const float4* src;
    if (t == 0) src = (const float4*)(feats + b * EE) + e4;
    else        src = (const float4*)(embW + (size_t)cap[b * TT + t - 1] * EE) + e4;
    float4 v = *src;
    ushort4 o;
    o.x = f2bf(v.x); o.y = f2bf(v.y); o.z = f2bf(v.z); o.w = f2bf(v.w);
    ((ushort4*)Xb)[(size_t)(t * BB + b) * 128 + e4] = o;
}

// ---------------- weight pack/convert kernels -------------------------------------
__global__ void cvt_bf16(const float* __restrict__ src, unsigned short* __restrict__ dst, int n)
{
    int i = blockIdx.x * 256 + threadIdx.x;
    if (i < n) dst[i] = f2bf(src[i]);
}

// attn_Wxb[n,e] = attn_W[n*1024 + e]
__global__ void pack_attn_wx(const float* __restrict__ attnW, unsigned short* __restrict__ dst)
{
    int i = blockIdx.x * 256 + threadIdx.x;    // 262,144
    int n = i >> 9, e = i & 511;
    dst[i] = f2bf(attnW[n * 1024 + e]);
}

// CxTb[e,n] = comb_W[n*1024 + e]
__global__ void pack_cxt(const float* __restrict__ combW, unsigned short* __restrict__ dst)
{
    int i = blockIdx.x * 256 + threadIdx.x;    // 262,144
    int e = i >> 9, n = i & 511;
    dst[i] = f2bf(combW[n * 1024 + e]);
}

// WaTb[m,n] = comb_W[n*1024 + 512 + m]
__global__ void pack_wat(const float* __restrict__ combW, unsigned short* __restrict__ dst)
{
    int i = blockIdx.x * 256 + threadIdx.x;    // 262,144
    int m = i >> 9, n = i & 511;
    dst[i] = f2bf(combW[n * 1024 + 512 + m]);
}

// Wcatb[j,k]: j<512 -> attn_W[j,512+k]; else Whh[j-512,k]
__global__ void pack_wcat_bf(const float* __restrict__ attnW, const float* __restrict__ Whh,
                             unsigned short* __restrict__ dst)
{
    int i = blockIdx.x * 256 + threadIdx.x;    // 1,048,576
    int j = i >> 9, k = i & 511;
    dst[i] = f2bf((j < 512) ? attnW[j * 1024 + 512 + k]
                            : Whh[(size_t)(j - 512) * 512 + k]);
}

// bias2[j] = bih[j] + dot(Wih[j,:], comb_b)
__global__ void bias2_kernel(const float* __restrict__ Wih, const float* __restrict__ comb_b,
                             const float* __restrict__ bih, float* __restrict__ bias2)
{
    int j = blockIdx.x, lane = threadIdx.x;   // grid 1536, block 64
    float s = 0.f;
    for (int n = lane; n < 512; n += 64) s += Wih[(size_t)j * 512 + n] * comb_b[n];
    for (int o = 32; o > 0; o >>= 1) s += __shfl_down(s, o);
    if (lane == 0) bias2[j] = bih[j] + s;
}

// ---------------- fused per-step kernel 2: softmax + APP + GX gemm + GRU gate ------
// grid = 16 blocks x 256. Each block:
//   phase 1: full softmax over AB[:,0:512] for all 128 rows, APP = feats*aw -> LDS (bf16, swizzled)
//   phase 2: GX[:, n0..n0+31] trio = APP @ W_ac^T slices (A from LDS, B from global)
//            + GRU gate + h writeback for its 32 n-columns.
__global__ __launch_bounds__(256) void sm_gx_gate(
    const float* __restrict__ AB,          // [128,2048]
    const float* __restrict__ feats,       // [128,512]
    const unsigned short* __restrict__ W_acb, // [1536,512] bf16
    const float* __restrict__ GxXt,        // [128,1536]
    const float* __restrict__ hprev,       // [128,512]
    float* __restrict__ HSt,               // [128,512]
    unsigned short* __restrict__ HSbt)     // [128,512] bf16
{
    __shared__ __align__(16) unsigned char APP[128 * 1024];  // [128][512] bf16, swizzled
    const int tid = threadIdx.x;
    const int lane = tid & 63, wave = tid >> 6;
    const int m16 = lane & 15, q = lane >> 4;

    // ---- phase 1: softmax + APP (each wave handles 32 rows) ----
    for (int r = wave; r < 128; r += 4) {
        const float* Lr = AB + r * 2048 + lane * 8;
        float4 x0 = *(const float4*)(Lr);
        float4 x1 = *(const float4*)(Lr + 4);
        float vm = fmaxf(fmaxf(fmaxf(x0.x, x0.y), fmaxf(x0.z, x0.w)),
                         fmaxf(fmaxf(x1.x, x1.y), fmaxf(x1.z, x1.w)));
#pragma unroll
        for (int o = 32; o > 0; o >>= 1) vm = fmaxf(vm, __shfl_xor(vm, o));
        float e0 = __expf(x0.x - vm), e1 = __expf(x0.y - vm);
        float e2 = __expf(x0.z - vm), e3 = __expf(x0.w - vm);
        float e4 = __expf(x1.x - vm), e5 = __expf(x1.y - vm);
        float e6 = __expf(x1.z - vm), e7 = __expf(x1.w - vm);
        float s = ((e0 + e1) + (e2 + e3)) + ((e4 + e5) + (e6 + e7));
#pragma unroll
        for (int o = 32; o > 0; o >>= 1) s += __shfl_xor(s, o);
        const float inv = 1.f / s;
        const float* fr = feats + r * 512 + lane * 8;
        float4 f0 = *(const float4*)(fr);
        float4 f1 = *(const float4*)(fr + 4);
        s16x8_t ov;
        ov[0] = (short)f2bf(f0.x * e0 * inv);
        ov[1] = (short)f2bf(f0.y * e1 * inv);
        ov[2] = (short)f2bf(f0.z * e2 * inv);
        ov[3] = (short)f2bf(f0.w * e3 * inv);
        ov[4] = (short)f2bf(f1.x * e4 * inv);
        ov[5] = (short)f2bf(f1.y * e5 * inv);
        ov[6] = (short)f2bf(f1.z * e6 * inv);
        ov[7] = (short)f2bf(f1.w * e7 * inv);
        *(s16x8_t*)(APP + swz(r, lane * 16)) = ov;
    }
    __syncthreads();

    // ---- phase 2: GX trio gemm (A = APP from LDS, B = W_ac slice from global) ----
    const int n0 = blockIdx.x * 32;
    const int rowhalf = (wave >> 1) * 64;
    const int j = wave & 1;
    f32x4_t acc[4][3];
#pragma unroll
    for (int i = 0; i < 4; i++)
#pragma unroll
        for (int p = 0; p < 3; p++)
            acc[i][p] = (f32x4_t){0.f, 0.f, 0.f, 0.f};
    for (int kc = 0; kc < 512; kc += 32) {
        const int kb = (kc + q * 8) * 2;
        s16x8_t af[4];
#pragma unroll
        for (int i = 0; i < 4; i++)
            af[i] = *(const s16x8_t*)(APP + swz(rowhalf + i * 16 + m16, kb));
        s16x8_t bfr[3];
#pragma unroll
        for (int p = 0; p < 3; p++)
            bfr[p] = *(const s16x8_t*)(W_acb +
                (size_t)(p * 512 + n0 + j * 16 + m16) * 512 + kc + q * 8);
#pragma unroll
        for (int i = 0; i < 4; i++)
#pragma unroll
            for (int p = 0; p < 3; p++)
                acc[i][p] = __builtin_amdgcn_mfma_f32_16x16x32_bf16(af[i], bfr[p], acc[i][p], 0, 0, 0);
    }

    // ---- GRU gate + h writeback ----
    const int n = n0 + j * 16 + m16;
#pragma unroll
    for (int i = 0; i < 4; i++) {
        const int b0 = rowhalf + i * 16 + q * 4;
#pragma unroll
        for (int rr = 0; rr < 4; rr++) {
            const int b = b0 + rr;
            float xr = acc[i][0][rr] + GxXt[b * 1536 + n];
            float xz = acc[i][1][rr] + GxXt[b * 1536 + 512 + n];
            float xn = acc[i][2][rr] + GxXt[b * 1536 + 1024 + n];
            float hr = AB[b * 2048 + 512 + n];
            float hz = AB[b * 2048 + 1024 + n];
            float hn = AB[b * 2048 + 1536 + n];
            float r = 1.f / (1.f + __expf(-(xr + hr)));
            float z = 1.f / (1.f + __expf(-(xz + hz)));
            float nt = tanhf(xn + r * hn);
            float h = (1.f - z) * nt + z * hprev[b * 512 + n];
            HSt[b * 512 + n] = h;
            HSbt[b * 512 + n] = f2bf(h);
        }
    }
}

// ---------------- fused log-softmax: one read + one write per row ------------------
__global__ __launch_bounds__(256) void logsoftmax_k(float* __restrict__ C)
{
    __shared__ float4 buf[2500];   // one 10000-float row (40 KB)
    __shared__ float red[8];
    const int row = blockIdx.x, tid = threadIdx.x;
    float4* p = (float4*)(C + (size_t)row * VV);
    float m = -1e30f;
    for (int i = tid; i < 2500; i += 256) {
        float4 v = p[i];
        buf[i] = v;
        m = fmaxf(fmaxf(fmaxf(v.x, v.y), fmaxf(v.z, v.w)), m);
    }
#pragma unroll
    for (int o = 32; o > 0; o >>= 1) m = fmaxf(m, __shfl_xor(m, o));
    if ((tid & 63) == 0) red[tid >> 6] = m;
    __syncthreads();
    m = fmaxf(fmaxf(red[0], red[1]), fmaxf(red[2], red[3]));
    float s = 0.f;
    for (int i = tid; i < 2500; i += 256) {
        float4 v = buf[i];
        s += __expf(v.x - m) + __expf(v.y - m) + __expf(v.z - m) + __expf(v.w - m);
    }
#pragma unroll
    for (int o = 32; o > 0; o >>= 1) s += __shfl_xor(s, o);
    if ((tid & 63) == 0) red[4 + (tid >> 6)] = s;
    __syncthreads();
    const float l = m + logf(red[4] + red[5] + red[6] + red[7]);
    for (int i = tid; i < 2500; i += 256) {
        float4 v = buf[i];
        v.x -= l; v.y -= l; v.z -= l; v.w -= l;
        p[i] = v;
    }
}

// ---------------- hiddens: [T,B,H] -> [B,T,H] -------------------------------------
__global__ void copy_hiddens(const float* __restrict__ HS, float* __restrict__ out)
{
    int id = blockIdx.x * 256 + threadIdx.x;   // 1,048,576 float4
    int h4 = id & 127;
    int t = (id >> 7) & 63;
    int b = id >> 13;
    ((float4*)out)[id] = ((const float4*)HS)[t * 16384 + b * 128 + h4];
}

// ===================================================================================
extern "C" void kernel_launch(void* const* d_in, const int* in_sizes, int n_in,
                              void* d_out, int out_size, void* d_ws, size_t ws_size,
                              hipStream_t stream)
{
    const float* features = (const float*)d_in[0];
    const int*   captions = (const int*)d_in[1];
    const float* h0       = (const float*)d_in[2];
    const float* embed_W  = (const float*)d_in[4];
    const float* fc_W     = (const float*)d_in[5];
    const float* fc_b     = (const float*)d_in[6];
    const float* bn_gamma = (const float*)d_in[7];
    const float* bn_beta  = (const float*)d_in[8];
    const float* attn_W   = (const float*)d_in[9];
    const float* attn_b   = (const float*)d_in[10];
    const float* comb_W   = (const float*)d_in[11];
    const float* comb_b   = (const float*)d_in[12];
    const float* gru_Wih  = (const float*)d_in[13];
    const float* gru_Whh  = (const float*)d_in[14];
    const float* gru_bih  = (const float*)d_in[15];
    const float* gru_bhh  = (const float*)d_in[16];
    const float* out_W    = (const float*)d_in[17];
    const float* out_b    = (const float*)d_in[18];
    float* dout = (float*)d_out;

    // workspace layout
    float* w      = (float*)d_ws;
    float* f      = w;                    //    65,536
    float* feats  = w + 65536;            //    65,536
    float* Lx     = w + 131072;           // 4,194,304
    float* GxX    = w + 4325376;          // 12,582,912
    float* HS     = w + 16908288;         // 4,194,304
    float* W2     = w + 21102592;         //   786,432
    float* W_ac   = w + 21889024;         //   786,432
    float* AB     = w + 22675456;         //   262,144
    float* bias2  = w + 23134208;         //     1,536
    unsigned short* u      = (unsigned short*)(w + 23143936);
    unsigned short* Xb     = u;             // 4,194,304
    unsigned short* attnWxb= u + 4194304;   //   262,144
    unsigned short* Wihb   = u + 4456448;   //   786,432
    unsigned short* CxTb   = u + 5242880;   //   262,144
    unsigned short* WaTb   = u + 5505024;   //   262,144
    unsigned short* Wcatb  = u + 5767168;   // 1,048,576
    unsigned short* W2b    = u + 6815744;   //   786,432
    unsigned short* W_acb  = u + 7602176;   //   786,432
    unsigned short* outWb  = u + 8388608;   // 5,120,000
    unsigned short* HSb    = u + 13508608;  // 4,194,304
    unsigned short* h0b    = u + 17768448;  //    65,536

    dim3 blk2(16, 16);

    // ---- prep ----
    gemm32<<<dim3(16, 4), blk2, 0, stream>>>(features, FIN, fc_W, FIN, f, EE, FIN, fc_b);
    bn_kernel<<<512, 128, 0, stream>>>(f, bn_gamma, bn_beta, feats);
    cvt_bf16<<<256, 256, 0, stream>>>(h0, h0b, BB * HH);
    build_x_bf16<<<4096, 256, 0, stream>>>(feats, embed_W, captions, Xb);
    pack_attn_wx<<<1024, 256, 0, stream>>>(attn_W, attnWxb);
    pack_cxt<<<1024, 256, 0, stream>>>(comb_W, CxTb);
    pack_wat<<<1024, 256, 0, stream>>>(comb_W, WaTb);
    pack_wcat_bf<<<4096, 256, 0, stream>>>(attn_W, gru_Whh, Wcatb);
    cvt_bf16<<<3072, 256, 0, stream>>>(gru_Wih, Wihb, 1536 * 512);
    cvt_bf16<<<20000, 256, 0, stream>>>(out_W, outWb, VV * HH);
    bias2_kernel<<<1536, 64, 0, stream>>>(gru_Wih, comb_b, gru_bih, bias2);

    // Lx = X @ attn_Wx^T + attn_b        [8192, 512]
    gemm128<<<dim3(4, 64), 256, 0, stream>>>(Xb, attnWxb, Lx, 512, 512,
                                             attn_b, nullptr, 0, 0);
    // W2 = Wih @ comb_Wx                  [1536, 512]
    gemm64<<<dim3(8, 24), 256, 0, stream>>>(Wihb, CxTb, W2, 512, 512,
                                            nullptr, nullptr, 0, 0);
    cvt_bf16<<<3072, 256, 0, stream>>>(W2, W2b, 1536 * 512);
    // GxX = X @ W2^T + bias2              [8192, 1536]
    gemm128<<<dim3(12, 64), 256, 0, stream>>>(Xb, W2b, GxX, 1536, 512,
                                              bias2, nullptr, 0, 0);
    // W_ac = Wih @ comb_Wa                [1536, 512]
    gemm64<<<dim3(8, 24), 256, 0, stream>>>(Wihb, WaTb, W_ac, 512, 512,
                                            nullptr, nullptr, 0, 0);
    cvt_bf16<<<3072, 256, 0, stream>>>(W_ac, W_acb, 1536 * 512);

    // ---- recurrence: 2 launches per step ----
    for (int t = 0; t < TT; t++) {
        const unsigned short* hb = (t == 0) ? h0b : (HSb + (size_t)(t - 1) * BB * HH);
        const float* hprev = (t == 0) ? h0 : (HS + (size_t)(t - 1) * BB * HH);
        // AB = [ Lx_t + h@attn_Wh^T  |  bhh + h@Whh^T ]   [128, 2048]
        gemm64<<<dim3(32, 2), 256, 0, stream>>>(hb, Wcatb, AB, 2048, 512,
                                                gru_bhh, Lx + (size_t)t * BB * HH, 512, 1);
        // softmax + APP (LDS) + GX trio + GRU gate
        sm_gx_gate<<<16, 256, 0, stream>>>(AB, feats, W_acb,
                                           GxX + (size_t)t * BB * 1536, hprev,
                                           HS + (size_t)t * BB * HH,
                                           HSb + (size_t)t * BB * HH);
    }

    // ---- output head ----
    gemm128<<<dim3(79, 64), 256, 0, stream>>>(HSb, outWb, dout, VV, 512,
                                              out_b, nullptr, 0, 0);
    logsoftmax_k<<<8192, 256, 0, stream>>>(dout);
    copy_hiddens<<<4096, 256, 0, stream>>>(HS, dout + (size_t)TT * BB * VV);
}

// Round 3
// 3287.982 us; speedup vs baseline: 1.4396x; 1.2526x over previous
//
#include <hip/hip_runtime.h>

// Model dims
#define BB 128
#define TT 64
#define EE 512
#define HH 512
#define VV 10000
#define FIN 2048

typedef __attribute__((ext_vector_type(4))) float f32x4_t;
typedef __attribute__((ext_vector_type(8))) short s16x8_t;

__device__ __forceinline__ unsigned short f2bf(float x) {
    unsigned int u = __float_as_uint(x);
    unsigned int r = (u + 0x7fffu + ((u >> 16) & 1u)) >> 16;
    return (unsigned short)r;
}

// XOR swizzle for LDS tiles with 1024 B row stride (512 bf16 cols).
// 16 lanes reading the same 16B k-slot of 16 consecutive rows spread over
// 8 distinct 16B slots -> 2-way bank aliasing (free).
__device__ __forceinline__ int swz(int row, int kb) {
    return row * 1024 + (kb ^ ((row & 7) << 4));
}

// ---------------- fp32 GEMM (fc layer only): C[M,N] = A[M,K] @ B[N,K]^T + bias -----
__global__ __launch_bounds__(256) void gemm32(
    const float* __restrict__ A, int lda,
    const float* __restrict__ Bw, int ldb,
    float* __restrict__ C, int ldc, int K,
    const float* __restrict__ bias)
{
    __shared__ float As[32][34];
    __shared__ float Bs[32][34];
    const int tx = threadIdx.x, ty = threadIdx.y;
    const int tid = ty * 16 + tx;
    const int m0 = blockIdx.y * 32, n0 = blockIdx.x * 32;
    const int lr = tid >> 3, lc = (tid & 7) << 2;
    const float* ap = A + (size_t)(m0 + lr) * lda + lc;
    const float* bp = Bw + (size_t)(n0 + lr) * ldb + lc;
    float c00 = 0.f, c01 = 0.f, c10 = 0.f, c11 = 0.f;
    for (int kc = 0; kc < K; kc += 32) {
        float4 av = *(const float4*)(ap + kc);
        float4 bv = *(const float4*)(bp + kc);
        __syncthreads();
        As[lc + 0][lr] = av.x; As[lc + 1][lr] = av.y;
        As[lc + 2][lr] = av.z; As[lc + 3][lr] = av.w;
        Bs[lc + 0][lr] = bv.x; Bs[lc + 1][lr] = bv.y;
        Bs[lc + 2][lr] = bv.z; Bs[lc + 3][lr] = bv.w;
        __syncthreads();
#pragma unroll
        for (int kk = 0; kk < 32; kk++) {
            float2 a = *(const float2*)&As[kk][2 * ty];
            float2 b = *(const float2*)&Bs[kk][2 * tx];
            c00 = fmaf(a.x, b.x, c00); c01 = fmaf(a.x, b.y, c01);
            c10 = fmaf(a.y, b.x, c10); c11 = fmaf(a.y, b.y, c11);
        }
    }
    float cc[2][2] = {{c00, c01}, {c10, c11}};
    const int row = m0 + 2 * ty, col = n0 + 2 * tx;
#pragma unroll
    for (int i = 0; i < 2; i++)
#pragma unroll
        for (int j = 0; j < 2; j++)
            C[(size_t)(row + i) * ldc + col + j] = cc[i][j] + bias[col + j];
}

// ---------------- bf16 MFMA GEMM, 128x128 tile ------------------------------------
// C[M,N] = A[M,K]@B[N,K]^T, M%128==0, K%32==0. grid=(ceil(N/128), M/128).
__global__ __launch_bounds__(256) void gemm128(
    const unsigned short* __restrict__ A, const unsigned short* __restrict__ Bw,
    float* __restrict__ C, int N, int K,
    const float* __restrict__ bias,
    const float* __restrict__ base, int ldbase, int mode)
{
    __shared__ __align__(16) unsigned short As[128 * 32];
    __shared__ __align__(16) unsigned short Bs[128 * 32];
    const int tid = threadIdx.x;
    const int lane = tid & 63, wave = tid >> 6;
    const int bm = blockIdx.y * 128, bn = blockIdx.x * 128;
    const int wm = (wave & 1) * 64, wn = (wave >> 1) * 64;
    const int sr = tid >> 2, sc = (tid & 3) * 8;
    const int m16 = lane & 15, q = lane >> 4;

    f32x4_t acc[4][4];
#pragma unroll
    for (int i = 0; i < 4; i++)
#pragma unroll
        for (int j = 0; j < 4; j++)
            acc[i][j] = (f32x4_t){0.f, 0.f, 0.f, 0.f};

    for (int kc = 0; kc < K; kc += 32) {
        uint4 a0 = *(const uint4*)(A + (size_t)(bm + sr) * K + kc + sc);
        uint4 a1 = *(const uint4*)(A + (size_t)(bm + 64 + sr) * K + kc + sc);
        uint4 b0, b1;
        int rb0 = bn + sr, rb1 = bn + 64 + sr;
        if (rb0 < N) b0 = *(const uint4*)(Bw + (size_t)rb0 * K + kc + sc);
        else { b0.x = 0; b0.y = 0; b0.z = 0; b0.w = 0; }
        if (rb1 < N) b1 = *(const uint4*)(Bw + (size_t)rb1 * K + kc + sc);
        else { b1.x = 0; b1.y = 0; b1.z = 0; b1.w = 0; }
        __syncthreads();
        *(uint4*)(&As[sr * 32 + sc]) = a0;
        *(uint4*)(&As[(sr + 64) * 32 + sc]) = a1;
        *(uint4*)(&Bs[sr * 32 + sc]) = b0;
        *(uint4*)(&Bs[(sr + 64) * 32 + sc]) = b1;
        __syncthreads();

        s16x8_t af[4], bf[4];
#pragma unroll
        for (int i = 0; i < 4; i++) {
            af[i] = *(const s16x8_t*)(&As[(wm + i * 16 + m16) * 32 + q * 8]);
            bf[i] = *(const s16x8_t*)(&Bs[(wn + i * 16 + m16) * 32 + q * 8]);
        }
#pragma unroll
        for (int i = 0; i < 4; i++)
#pragma unroll
            for (int j = 0; j < 4; j++)
                acc[i][j] = __builtin_amdgcn_mfma_f32_16x16x32_bf16(af[i], bf[j], acc[i][j], 0, 0, 0);
    }

#pragma unroll
    for (int i = 0; i < 4; i++)
#pragma unroll
        for (int j = 0; j < 4; j++) {
            int gr = bm + wm + i * 16 + q * 4;
            int gc = bn + wn + j * 16 + m16;
            if (gc < N) {
                if (mode == 0) {
                    float addc = bias ? bias[gc] : 0.f;
#pragma unroll
                    for (int rr = 0; rr < 4; rr++) {
                        float v = acc[i][j][rr] + addc;
                        if (base) v += base[(size_t)(gr + rr) * ldbase + gc];
                        C[(size_t)(gr + rr) * N + gc] = v;
                    }
                } else {
#pragma unroll
                    for (int rr = 0; rr < 4; rr++) {
                        int r = gr + rr;
                        float v = acc[i][j][rr];
                        v += (gc < 512) ? base[r * 512 + gc] : bias[gc - 512];
                        C[(size_t)r * N + gc] = v;
                    }
                }
            }
        }
}

// ---------------- bf16 MFMA GEMM, 64x64 tile --------------------------------------
__global__ __launch_bounds__(256) void gemm64(
    const unsigned short* __restrict__ A, const unsigned short* __restrict__ Bw,
    float* __restrict__ C, int N, int K,
    const float* __restrict__ bias,
    const float* __restrict__ base, int ldbase, int mode)
{
    __shared__ __align__(16) unsigned short As[64 * 32];
    __shared__ __align__(16) unsigned short Bs[64 * 32];
    const int tid = threadIdx.x;
    const int lane = tid & 63, wave = tid >> 6;
    const int bm = blockIdx.y * 64, bn = blockIdx.x * 64;
    const int wm = (wave & 1) * 32, wn = (wave >> 1) * 32;
    const int sr = tid >> 2, sc = (tid & 3) * 8;
    const int m16 = lane & 15, q = lane >> 4;

    f32x4_t acc[2][2];
#pragma unroll
    for (int i = 0; i < 2; i++)
#pragma unroll
        for (int j = 0; j < 2; j++)
            acc[i][j] = (f32x4_t){0.f, 0.f, 0.f, 0.f};

    for (int kc = 0; kc < K; kc += 32) {
        uint4 a0 = *(const uint4*)(A + (size_t)(bm + sr) * K + kc + sc);
        uint4 b0 = *(const uint4*)(Bw + (size_t)(bn + sr) * K + kc + sc);
        __syncthreads();
        *(uint4*)(&As[sr * 32 + sc]) = a0;
        *(uint4*)(&Bs[sr * 32 + sc]) = b0;
        __syncthreads();

        s16x8_t af[2], bf[2];
#pragma unroll
        for (int i = 0; i < 2; i++) {
            af[i] = *(const s16x8_t*)(&As[(wm + i * 16 + m16) * 32 + q * 8]);
            bf[i] = *(const s16x8_t*)(&Bs[(wn + i * 16 + m16) * 32 + q * 8]);
        }
#pragma unroll
        for (int i = 0; i < 2; i++)
#pragma unroll
            for (int j = 0; j < 2; j++)
                acc[i][j] = __builtin_amdgcn_mfma_f32_16x16x32_bf16(af[i], bf[j], acc[i][j], 0, 0, 0);
    }

#pragma unroll
    for (int i = 0; i < 2; i++)
#pragma unroll
        for (int j = 0; j < 2; j++) {
            int gr = bm + wm + i * 16 + q * 4;
            int gc = bn + wn + j * 16 + m16;
            if (mode == 0) {
                float addc = bias ? bias[gc] : 0.f;
#pragma unroll
                for (int rr = 0; rr < 4; rr++) {
                    float v = acc[i][j][rr] + addc;
                    if (base) v += base[(size_t)(gr + rr) * ldbase + gc];
                    C[(size_t)(gr + rr) * N + gc] = v;
                }
            } else {
#pragma unroll
                for (int rr = 0; rr < 4; rr++) {
                    int r = gr + rr;
                    float v = acc[i][j][rr];
                    v += (gc < 512) ? base[r * 512 + gc] : bias[gc - 512];
                    C[(size_t)r * N + gc] = v;
                }
            }
        }
}

// ---------------- BatchNorm1d (training stats over B=128) --------------------------
__global__ __launch_bounds__(128) void bn_kernel(
    const float* __restrict__ f, const float* __restrict__ gamma,
    const float* __restrict__ beta, float* __restrict__ feats)
{
    int e = blockIdx.x, b = threadIdx.x;
    float v = f[b * EE + e];
    __shared__ float s1[128], s2[128];
    s1[b] = v; s2[b] = v * v;
    __syncthreads();
    for (int s = 64; s > 0; s >>= 1) {
        if (b < s) { s1[b] += s1[b + s]; s2[b] += s2[b + s]; }
        __syncthreads();
    }
    float mu = s1[0] * (1.f / 128.f);
    float var = s2[0] * (1.f / 128.f) - mu * mu;
    float inv = 1.f / sqrtf(var + 1e-5f);
    feats[b * EE + e] = gamma[e] * (v - mu) * inv + beta[e];
}

// ---------------- build Xb[t][b][:] in bf16 ---------------------------------------
__global__ void build_x_bf16(const float* __restrict__ feats, const float* __restrict__ embW,
                             const int* __restrict__ cap, unsigned short* __restrict__ Xb)
{
    int id = blockIdx.x * 256 + threadIdx.x;   // 1,048,576 groups of 4
    int e4 = id & 127;
    int rem = id >> 7;
    int b = rem & 127;
    int t = rem >> 7;
    const float4* src;
    if (t == 0) src = (const float4*)(feats + b * EE) + e4;
    else        src = (const float4*)(embW + (size_t)cap[b * TT + t - 1] * EE) + e4;
    float4 v = *src;
    ushort4 o;
    o.x = f2bf(v.x); o.y = f2bf(v.y); o.z = f2bf(v.z); o.w = f2bf(v.w);
    ((ushort4*)Xb)[(size_t)(t * BB + b) * 128 + e4] = o;
}

// ---------------- weight pack/convert kernels -------------------------------------
__global__ void cvt_bf16(const float* __restrict__ src, unsigned short* __restrict__ dst, int n)
{
    int i = blockIdx.x * 256 + threadIdx.x;
    if (i < n) dst[i] = f2bf(src[i]);
}

// attn_Wxb[n,e] = attn_W[n*1024 + e]
__global__ void pack_attn_wx(const float* __restrict__ attnW, unsigned short* __restrict__ dst)
{
    int i = blockIdx.x * 256 + threadIdx.x;    // 262,144
    int n = i >> 9, e = i & 511;
    dst[i] = f2bf(attnW[n * 1024 + e]);
}

// CxTb[e,n] = comb_W[n*1024 + e]
__global__ void pack_cxt(const float* __restrict__ combW, unsigned short* __restrict__ dst)
{
    int i = blockIdx.x * 256 + threadIdx.x;    // 262,144
    int e = i >> 9, n = i & 511;
    dst[i] = f2bf(combW[n * 1024 + e]);
}

// WaTb[m,n] = comb_W[n*1024 + 512 + m]
__global__ void pack_wat(const float* __restrict__ combW, unsigned short* __restrict__ dst)
{
    int i = blockIdx.x * 256 + threadIdx.x;    // 262,144
    int m = i >> 9, n = i & 511;
    dst[i] = f2bf(combW[n * 1024 + 512 + m]);
}

// Wcatb[j,k]: j<512 -> attn_W[j,512+k]; else Whh[j-512,k]
__global__ void pack_wcat_bf(const float* __restrict__ attnW, const float* __restrict__ Whh,
                             unsigned short* __restrict__ dst)
{
    int i = blockIdx.x * 256 + threadIdx.x;    // 1,048,576
    int j = i >> 9, k = i & 511;
    dst[i] = f2bf((j < 512) ? attnW[j * 1024 + 512 + k]
                            : Whh[(size_t)(j - 512) * 512 + k]);
}

// bias2[j] = bih[j] + dot(Wih[j,:], comb_b)
__global__ void bias2_kernel(const float* __restrict__ Wih, const float* __restrict__ comb_b,
                             const float* __restrict__ bih, float* __restrict__ bias2)
{
    int j = blockIdx.x, lane = threadIdx.x;   // grid 1536, block 64
    float s = 0.f;
    for (int n = lane; n < 512; n += 64) s += Wih[(size_t)j * 512 + n] * comb_b[n];
    for (int o = 32; o > 0; o >>= 1) s += __shfl_down(s, o);
    if (lane == 0) bias2[j] = bih[j] + s;
}

// ---------------- fused per-step kernel 2: softmax + APP + GX gemm + GRU gate ------
// grid = 32 blocks x 512 threads (8 waves). Block owns GX cols n0..n0+15 (x3 parts).
//   phase 1: softmax over AB[:,0:512] for all 128 rows (16 rows/wave),
//            APP = feats*aw -> LDS (bf16, swizzled)
//   phase 2: GX[:, n] trio = APP @ W_ac^T slices (A from LDS, B from global L2)
//            + GRU gate + h writeback for its 16 n-columns.
__global__ __launch_bounds__(512) void sm_gx_gate(
    const float* __restrict__ AB,          // [128,2048]
    const float* __restrict__ feats,       // [128,512]
    const unsigned short* __restrict__ W_acb, // [1536,512] bf16
    const float* __restrict__ GxXt,        // [128,1536]
    const float* __restrict__ hprev,       // [128,512]
    float* __restrict__ HSt,               // [128,512]
    unsigned short* __restrict__ HSbt)     // [128,512] bf16
{
    __shared__ __align__(16) unsigned char APP[128 * 1024];  // [128][512] bf16, swizzled
    const int tid = threadIdx.x;
    const int lane = tid & 63, wave = tid >> 6;   // 8 waves
    const int m16 = lane & 15, q = lane >> 4;

    // ---- phase 1: softmax + APP (each wave handles 16 rows) ----
    for (int r = wave; r < 128; r += 8) {
        const float* Lr = AB + r * 2048 + lane * 8;
        float4 x0 = *(const float4*)(Lr);
        float4 x1 = *(const float4*)(Lr + 4);
        float vm = fmaxf(fmaxf(fmaxf(x0.x, x0.y), fmaxf(x0.z, x0.w)),
                         fmaxf(fmaxf(x1.x, x1.y), fmaxf(x1.z, x1.w)));
#pragma unroll
        for (int o = 32; o > 0; o >>= 1) vm = fmaxf(vm, __shfl_xor(vm, o));
        float e0 = __expf(x0.x - vm), e1 = __expf(x0.y - vm);
        float e2 = __expf(x0.z - vm), e3 = __expf(x0.w - vm);
        float e4 = __expf(x1.x - vm), e5 = __expf(x1.y - vm);
        float e6 = __expf(x1.z - vm), e7 = __expf(x1.w - vm);
        float s = ((e0 + e1) + (e2 + e3)) + ((e4 + e5) + (e6 + e7));
#pragma unroll
        for (int o = 32; o > 0; o >>= 1) s += __shfl_xor(s, o);
        const float inv = 1.f / s;
        const float* fr = feats + r * 512 + lane * 8;
        float4 f0 = *(const float4*)(fr);
        float4 f1 = *(const float4*)(fr + 4);
        s16x8_t ov;
        ov[0] = (short)f2bf(f0.x * e0 * inv);
        ov[1] = (short)f2bf(f0.y * e1 * inv);
        ov[2] = (short)f2bf(f0.z * e2 * inv);
        ov[3] = (short)f2bf(f0.w * e3 * inv);
        ov[4] = (short)f2bf(f1.x * e4 * inv);
        ov[5] = (short)f2bf(f1.y * e5 * inv);
        ov[6] = (short)f2bf(f1.z * e6 * inv);
        ov[7] = (short)f2bf(f1.w * e7 * inv);
        *(s16x8_t*)(APP + swz(r, lane * 16)) = ov;
    }
    __syncthreads();

    // ---- phase 2: GX trio gemm (A = APP rows wave*16.., B = W_ac slice, global) ----
    const int n0 = blockIdx.x * 16;
    f32x4_t acc[3];
#pragma unroll
    for (int p = 0; p < 3; p++)
        acc[p] = (f32x4_t){0.f, 0.f, 0.f, 0.f};
    for (int kc = 0; kc < 512; kc += 32) {
        const int kb = (kc + q * 8) * 2;
        s16x8_t af = *(const s16x8_t*)(APP + swz(wave * 16 + m16, kb));
        s16x8_t bfr[3];
#pragma unroll
        for (int p = 0; p < 3; p++)
            bfr[p] = *(const s16x8_t*)(W_acb +
                (size_t)(p * 512 + n0 + m16) * 512 + kc + q * 8);
#pragma unroll
        for (int p = 0; p < 3; p++)
            acc[p] = __builtin_amdgcn_mfma_f32_16x16x32_bf16(af, bfr[p], acc[p], 0, 0, 0);
    }

    // ---- GRU gate + h writeback (wave covers b = wave*16 + q*4 + rr, n = n0+m16) ---
    const int n = n0 + m16;
    const int b0 = wave * 16 + q * 4;
#pragma unroll
    for (int rr = 0; rr < 4; rr++) {
        const int b = b0 + rr;
        float xr = acc[0][rr] + GxXt[b * 1536 + n];
        float xz = acc[1][rr] + GxXt[b * 1536 + 512 + n];
        float xn = acc[2][rr] + GxXt[b * 1536 + 1024 + n];
        float hr = AB[b * 2048 + 512 + n];
        float hz = AB[b * 2048 + 1024 + n];
        float hn = AB[b * 2048 + 1536 + n];
        float r = 1.f / (1.f + __expf(-(xr + hr)));
        float z = 1.f / (1.f + __expf(-(xz + hz)));
        float nt = tanhf(xn + r * hn);
        float h = (1.f - z) * nt + z * hprev[b * 512 + n];
        HSt[b * 512 + n] = h;
        HSbt[b * 512 + n] = f2bf(h);
    }
}

// ---------------- fused log-softmax: one read + one write per row ------------------
__global__ __launch_bounds__(256) void logsoftmax_k(float* __restrict__ C)
{
    __shared__ float4 buf[2500];   // one 10000-float row (40 KB)
    __shared__ float red[8];
    const int row = blockIdx.x, tid = threadIdx.x;
    float4* p = (float4*)(C + (size_t)row * VV);
    float m = -1e30f;
    for (int i = tid; i < 2500; i += 256) {
        float4 v = p[i];
        buf[i] = v;
        m = fmaxf(fmaxf(fmaxf(v.x, v.y), fmaxf(v.z, v.w)), m);
    }
#pragma unroll
    for (int o = 32; o > 0; o >>= 1) m = fmaxf(m, __shfl_xor(m, o));
    if ((tid & 63) == 0) red[tid >> 6] = m;
    __syncthreads();
    m = fmaxf(fmaxf(red[0], red[1]), fmaxf(red[2], red[3]));
    float s = 0.f;
    for (int i = tid; i < 2500; i += 256) {
        float4 v = buf[i];
        s += __expf(v.x - m) + __expf(v.y - m) + __expf(v.z - m) + __expf(v.w - m);
    }
#pragma unroll
    for (int o = 32; o > 0; o >>= 1) s += __shfl_xor(s, o);
    if ((tid & 63) == 0) red[4 + (tid >> 6)] = s;
    __syncthreads();
    const float l = m + logf(red[4] + red[5] + red[6] + red[7]);
    for (int i = tid; i < 2500; i += 256) {
        float4 v = buf[i];
        v.x -= l; v.y -= l; v.z -= l; v.w -= l;
        p[i] = v;
    }
}

// ---------------- hiddens: [T,B,H] -> [B,T,H] -------------------------------------
__global__ void copy_hiddens(const float* __restrict__ HS, float* __restrict__ out)
{
    int id = blockIdx.x * 256 + threadIdx.x;   // 1,048,576 float4
    int h4 = id & 127;
    int t = (id >> 7) & 63;
    int b = id >> 13;
    ((float4*)out)[id] = ((const float4*)HS)[t * 16384 + b * 128 + h4];
}

// ===================================================================================
extern "C" void kernel_launch(void* const* d_in, const int* in_sizes, int n_in,
                              void* d_out, int out_size, void* d_ws, size_t ws_size,
                              hipStream_t stream)
{
    const float* features = (const float*)d_in[0];
    const int*   captions = (const int*)d_in[1];
    const float* h0       = (const float*)d_in[2];
    const float* embed_W  = (const float*)d_in[4];
    const float* fc_W     = (const float*)d_in[5];
    const float* fc_b     = (const float*)d_in[6];
    const float* bn_gamma = (const float*)d_in[7];
    const float* bn_beta  = (const float*)d_in[8];
    const float* attn_W   = (const float*)d_in[9];
    const float* attn_b   = (const float*)d_in[10];
    const float* comb_W   = (const float*)d_in[11];
    const float* comb_b   = (const float*)d_in[12];
    const float* gru_Wih  = (const float*)d_in[13];
    const float* gru_Whh  = (const float*)d_in[14];
    const float* gru_bih  = (const float*)d_in[15];
    const float* gru_bhh  = (const float*)d_in[16];
    const float* out_W    = (const float*)d_in[17];
    const float* out_b    = (const float*)d_in[18];
    float* dout = (float*)d_out;

    // workspace layout
    float* w      = (float*)d_ws;
    float* f      = w;                    //    65,536
    float* feats  = w + 65536;            //    65,536
    float* Lx     = w + 131072;           // 4,194,304
    float* GxX    = w + 4325376;          // 12,582,912
    float* HS     = w + 16908288;         // 4,194,304
    float* W2     = w + 21102592;         //   786,432
    float* W_ac   = w + 21889024;         //   786,432
    float* AB     = w + 22675456;         //   262,144
    float* bias2  = w + 23134208;         //     1,536
    unsigned short* u      = (unsigned short*)(w + 23143936);
    unsigned short* Xb     = u;             // 4,194,304
    unsigned short* attnWxb= u + 4194304;   //   262,144
    unsigned short* Wihb   = u + 4456448;   //   786,432
    unsigned short* CxTb   = u + 5242880;   //   262,144
    unsigned short* WaTb   = u + 5505024;   //   262,144
    unsigned short* Wcatb  = u + 5767168;   // 1,048,576
    unsigned short* W2b    = u + 6815744;   //   786,432
    unsigned short* W_acb  = u + 7602176;   //   786,432
    unsigned short* outWb  = u + 8388608;   // 5,120,000
    unsigned short* HSb    = u + 13508608;  // 4,194,304
    unsigned short* h0b    = u + 17768448;  //    65,536

    dim3 blk2(16, 16);

    // ---- prep ----
    gemm32<<<dim3(16, 4), blk2, 0, stream>>>(features, FIN, fc_W, FIN, f, EE, FIN, fc_b);
    bn_kernel<<<512, 128, 0, stream>>>(f, bn_gamma, bn_beta, feats);
    cvt_bf16<<<256, 256, 0, stream>>>(h0, h0b, BB * HH);
    build_x_bf16<<<4096, 256, 0, stream>>>(feats, embed_W, captions, Xb);
    pack_attn_wx<<<1024, 256, 0, stream>>>(attn_W, attnWxb);
    pack_cxt<<<1024, 256, 0, stream>>>(comb_W, CxTb);
    pack_wat<<<1024, 256, 0, stream>>>(comb_W, WaTb);
    pack_wcat_bf<<<4096, 256, 0, stream>>>(attn_W, gru_Whh, Wcatb);
    cvt_bf16<<<3072, 256, 0, stream>>>(gru_Wih, Wihb, 1536 * 512);
    cvt_bf16<<<20000, 256, 0, stream>>>(out_W, outWb, VV * HH);
    bias2_kernel<<<1536, 64, 0, stream>>>(gru_Wih, comb_b, gru_bih, bias2);

    // Lx = X @ attn_Wx^T + attn_b        [8192, 512]
    gemm128<<<dim3(4, 64), 256, 0, stream>>>(Xb, attnWxb, Lx, 512, 512,
                                             attn_b, nullptr, 0, 0);
    // W2 = Wih @ comb_Wx                  [1536, 512]
    gemm64<<<dim3(8, 24), 256, 0, stream>>>(Wihb, CxTb, W2, 512, 512,
                                            nullptr, nullptr, 0, 0);
    cvt_bf16<<<3072, 256, 0, stream>>>(W2, W2b, 1536 * 512);
    // GxX = X @ W2^T + bias2              [8192, 1536]
    gemm128<<<dim3(12, 64), 256, 0, stream>>>(Xb, W2b, GxX, 1536, 512,
                                              bias2, nullptr, 0, 0);
    // W_ac = Wih @ comb_Wa                [1536, 512]
    gemm64<<<dim3(8, 24), 256, 0, stream>>>(Wihb, WaTb, W_ac, 512, 512,
                                            nullptr, nullptr, 0, 0);
    cvt_bf16<<<3072, 256, 0, stream>>>(W_ac, W_acb, 1536 * 512);

    // ---- recurrence: 2 launches per step ----
    for (int t = 0; t < TT; t++) {
        const unsigned short* hb = (t == 0) ? h0b : (HSb + (size_t)(t - 1) * BB * HH);
        const float* hprev = (t == 0) ? h0 : (HS + (size_t)(t - 1) * BB * HH);
        // AB = [ Lx_t + h@attn_Wh^T  |  bhh + h@Whh^T ]   [128, 2048]
        gemm64<<<dim3(32, 2), 256, 0, stream>>>(hb, Wcatb, AB, 2048, 512,
                                                gru_bhh, Lx + (size_t)t * BB * HH, 512, 1);
        // softmax + APP (LDS) + GX trio + GRU gate
        sm_gx_gate<<<32, 512, 0, stream>>>(AB, feats, W_acb,
                                           GxX + (size_t)t * BB * 1536, hprev,
                                           HS + (size_t)t * BB * HH,
                                           HSb + (size_t)t * BB * HH);
    }

    // ---- output head ----
    gemm128<<<dim3(79, 64), 256, 0, stream>>>(HSb, outWb, dout, VV, 512,
                                              out_b, nullptr, 0, 0);
    logsoftmax_k<<<8192, 256, 0, stream>>>(dout);
    copy_hiddens<<<4096, 256, 0, stream>>>(HS, dout + (size_t)TT * BB * VV);
}